// Round 6
// baseline (511.921 us; speedup 1.0000x reference)
//
#include <hip/hip_runtime.h>
#include <hip/hip_cooperative_groups.h>

namespace cg = cooperative_groups;

// Problem constants
#define BS1 32
#define BS2 128
#define NEC 64
#define QD  256   // Q_DIM
#define MD  256   // MLP_DIM (== MEM_DIM)

// ---------------------------------------------------------------------------
// Fused cooperative kernel: 1024 blocks x 256 threads, all co-resident.
// Phase 1 (blocks 0..575):
//   [0,512):   proj_c rows 4*blk..+4      = crit @ W_mlp[:256,:]
//   [512,544): proj_e rows 4*(blk-512)..  = ehr  @ W_mlp[256:,:]
//   [544,576): att[b,:] = softmax_e(crit[b,e,:] . W_align[:256]), b = blk-544
// grid.sync()
// Phase 2: each block does 4 (b,p) pairs: h = att*(proj_c+proj_e)+b_mlp
// ---------------------------------------------------------------------------
__global__ __launch_bounds__(256, 4)
void fused_kernel(const float* __restrict__ crit,
                  const float* __restrict__ ehr,
                  const float* __restrict__ w_mlp,
                  const float* __restrict__ w_align,
                  const float* __restrict__ b_mlp,
                  float* __restrict__ proj_c,
                  float* __restrict__ proj_e,
                  float* __restrict__ att,
                  float* __restrict__ out) {
    __shared__ float As[4 * QD];       // 4-row A tile (4 KB) or wa[256]
    __shared__ float logits[NEC];
    int tid = threadIdx.x;
    int blk = blockIdx.x;

    // ---------------- Phase 1 ----------------
    if (blk < 544) {
        const float* A; const float* B; float* outp; int m0;
        if (blk < 512) { A = crit; B = w_mlp;           outp = proj_c; m0 = blk * 4; }
        else           { A = ehr;  B = w_mlp + QD * MD; outp = proj_e; m0 = (blk - 512) * 4; }
        // load 4 rows (1024 floats): 4 per thread
        *(float4*)&As[tid * 4] = *(const float4*)(A + m0 * QD + tid * 4);
        __syncthreads();
        int r = tid >> 6;            // row in [0,4)  (wave-uniform -> LDS broadcast)
        int c = (tid & 63) * 4;      // col base, wave covers 1 KB contiguous
        float acc[4] = {0.f, 0.f, 0.f, 0.f};
        #pragma unroll 4
        for (int k = 0; k < QD; ++k) {
            float a = As[r * QD + k];
            float4 b0 = *(const float4*)(B + k * MD + c);
            acc[0] = fmaf(a, b0.x, acc[0]);
            acc[1] = fmaf(a, b0.y, acc[1]);
            acc[2] = fmaf(a, b0.z, acc[2]);
            acc[3] = fmaf(a, b0.w, acc[3]);
        }
        *(float4*)(outp + (m0 + r) * MD + c) =
            make_float4(acc[0], acc[1], acc[2], acc[3]);
    } else if (blk < 576) {
        // ---- att for one b: 4 lanes per e-row ----
        int b = blk - 544;
        As[tid] = w_align[tid];            // wa[0:256]
        __syncthreads();
        int e = tid >> 2, q = tid & 3;
        const float* row = crit + (b * NEC + e) * QD + q * 64;
        const float* w   = &As[q * 64];
        float acc = 0.f;
        #pragma unroll
        for (int k = 0; k < 64; k += 4) {
            float4 u = *(const float4*)(row + k);
            acc = fmaf(u.x, w[k + 0], acc);
            acc = fmaf(u.y, w[k + 1], acc);
            acc = fmaf(u.z, w[k + 2], acc);
            acc = fmaf(u.w, w[k + 3], acc);
        }
        acc += __shfl_xor(acc, 1);
        acc += __shfl_xor(acc, 2);
        if (q == 0) logits[e] = acc;
        __syncthreads();
        if (tid < NEC) {                   // wave 0: 64-wide softmax
            float l = logits[tid];
            float m = l;
            #pragma unroll
            for (int off = 32; off; off >>= 1) m = fmaxf(m, __shfl_xor(m, off));
            float ex = __expf(l - m);
            float s = ex;
            #pragma unroll
            for (int off = 32; off; off >>= 1) s += __shfl_xor(s, off);
            att[b * NEC + tid] = ex / s;
        }
    }

    __threadfence();                       // make phase-1 stores device-visible
    cg::this_grid().sync();

    // ---------------- Phase 2 ----------------
    int wid = tid >> 6;                    // wave id [0,4)
    int d   = (tid & 63) * 4;              // [0,256) step 4
    #pragma unroll
    for (int i = 0; i < 4; ++i) {
        int bp = blk + i * 1024;           // [0,4096)
        int b = bp >> 7, p = bp & 127;

        const float4 pe = *(const float4*)(proj_e + p * MD + d);
        const float4 bm = *(const float4*)(b_mlp + d);

        const float* attp = att + b * NEC + wid;
        float a[16];
        #pragma unroll
        for (int pass = 0; pass < 16; ++pass) a[pass] = attp[pass * 4];

        const float* pc = proj_c + (b * NEC + wid) * MD + d;   // row e = wid
        float*       o  = out + (size_t)bp * (NEC * MD) + tid * 4;

        #pragma unroll
        for (int pass = 0; pass < 16; ++pass) {
            float4 c0 = *(const float4*)pc;
            float4 r0;
            r0.x = fmaf(a[pass], c0.x + pe.x, bm.x);
            r0.y = fmaf(a[pass], c0.y + pe.y, bm.y);
            r0.z = fmaf(a[pass], c0.z + pe.z, bm.z);
            r0.w = fmaf(a[pass], c0.w + pe.w, bm.w);
            *(float4*)o = r0;
            pc += 4 * MD;                  // e advances by 4 per pass
            o  += 1024;                    // 256 threads * 4 floats
        }
    }
}

// ---------------------------------------------------------------------------
// Fallback path (proven R5 kernels) in case cooperative launch is unavailable.
// ---------------------------------------------------------------------------
__global__ __launch_bounds__(256)
void prep_kernel(const float* __restrict__ crit,
                 const float* __restrict__ ehr,
                 const float* __restrict__ w_mlp,
                 const float* __restrict__ w_align,
                 float* __restrict__ proj_c,
                 float* __restrict__ proj_e,
                 float* __restrict__ att) {
    __shared__ float smem[8 * QD];
    __shared__ float logits[NEC];
    int tid = threadIdx.x;
    int blk = blockIdx.x;

    if (blk < 272) {
        const float* A; const float* B; float* out; int m0;
        if (blk < 256) { A = crit; B = w_mlp;           out = proj_c; m0 = blk * 8; }
        else           { A = ehr;  B = w_mlp + QD * MD; out = proj_e; m0 = (blk - 256) * 8; }
        {
            const float* src = A + m0 * QD + tid * 8;
            float4 a0 = *(const float4*)src;
            float4 a1 = *(const float4*)(src + 4);
            *(float4*)&smem[tid * 8]     = a0;
            *(float4*)&smem[tid * 8 + 4] = a1;
        }
        __syncthreads();
        int r = tid >> 5;
        int c = (tid & 31) * 8;
        float acc[8] = {0.f,0.f,0.f,0.f,0.f,0.f,0.f,0.f};
        #pragma unroll 4
        for (int k = 0; k < QD; ++k) {
            float a = smem[r * QD + k];
            const float* bp = B + k * MD + c;
            float4 b0 = *(const float4*)bp;
            float4 b1 = *(const float4*)(bp + 4);
            acc[0] = fmaf(a, b0.x, acc[0]);
            acc[1] = fmaf(a, b0.y, acc[1]);
            acc[2] = fmaf(a, b0.z, acc[2]);
            acc[3] = fmaf(a, b0.w, acc[3]);
            acc[4] = fmaf(a, b1.x, acc[4]);
            acc[5] = fmaf(a, b1.y, acc[5]);
            acc[6] = fmaf(a, b1.z, acc[6]);
            acc[7] = fmaf(a, b1.w, acc[7]);
        }
        float* o = out + (m0 + r) * MD + c;
        *(float4*)o       = make_float4(acc[0], acc[1], acc[2], acc[3]);
        *(float4*)(o + 4) = make_float4(acc[4], acc[5], acc[6], acc[7]);
    } else {
        int b = blk - 272;
        smem[tid] = w_align[tid];
        __syncthreads();
        int e = tid >> 2, q = tid & 3;
        const float* row = crit + (b * NEC + e) * QD + q * 64;
        const float* w   = &smem[q * 64];
        float acc = 0.f;
        #pragma unroll
        for (int k = 0; k < 64; k += 4) {
            float4 u = *(const float4*)(row + k);
            acc = fmaf(u.x, w[k + 0], acc);
            acc = fmaf(u.y, w[k + 1], acc);
            acc = fmaf(u.z, w[k + 2], acc);
            acc = fmaf(u.w, w[k + 3], acc);
        }
        acc += __shfl_xor(acc, 1);
        acc += __shfl_xor(acc, 2);
        if (q == 0) logits[e] = acc;
        __syncthreads();
        if (tid < NEC) {
            float l = logits[tid];
            float m = l;
            #pragma unroll
            for (int off = 32; off; off >>= 1) m = fmaxf(m, __shfl_xor(m, off));
            float ex = __expf(l - m);
            float s = ex;
            #pragma unroll
            for (int off = 32; off; off >>= 1) s += __shfl_xor(s, off);
            att[b * NEC + tid] = ex / s;
        }
    }
}

__global__ __launch_bounds__(256)
void final_kernel(const float* __restrict__ att,
                  const float* __restrict__ proj_c,
                  const float* __restrict__ proj_e,
                  const float* __restrict__ b_mlp,
                  float*       __restrict__ out) {
    int tid = threadIdx.x;
    int bp  = blockIdx.x;
    int b = bp >> 7, p = bp & 127;
    int wid = tid >> 6;
    int d   = (tid & 63) * 4;

    const float4 pe = *(const float4*)(proj_e + p * MD + d);
    const float4 bm = *(const float4*)(b_mlp + d);

    const float* attp = att + b * NEC + wid;
    float a[16];
    #pragma unroll
    for (int pass = 0; pass < 16; ++pass) a[pass] = attp[pass * 4];

    const float* pc = proj_c + (b * NEC + wid) * MD + d;
    float*       o  = out + (size_t)bp * (NEC * MD) + tid * 4;

    #pragma unroll
    for (int pass = 0; pass < 16; ++pass) {
        float4 c0 = *(const float4*)pc;
        float4 r0;
        r0.x = fmaf(a[pass], c0.x + pe.x, bm.x);
        r0.y = fmaf(a[pass], c0.y + pe.y, bm.y);
        r0.z = fmaf(a[pass], c0.z + pe.z, bm.z);
        r0.w = fmaf(a[pass], c0.w + pe.w, bm.w);
        *(float4*)o = r0;
        pc += 4 * MD;
        o  += 1024;
    }
}

extern "C" void kernel_launch(void* const* d_in, const int* in_sizes, int n_in,
                              void* d_out, int out_size, void* d_ws, size_t ws_size,
                              hipStream_t stream) {
    // setup_inputs order: ehr_vector, criteria, ec_mask, W_align, b_align, W_mlp, b_mlp
    const float* ehr     = (const float*)d_in[0];   // (128, 256) fp32
    const float* crit    = (const float*)d_in[1];   // (32, 64, 256) fp32
    const float* w_align = (const float*)d_in[3];   // (512,) -> use [:256]
    const float* w_mlp   = (const float*)d_in[5];   // (512, 256) row-major fp32
    const float* b_mlp   = (const float*)d_in[6];   // (256,)
    float* out = (float*)d_out;                      // (32,128,64,256) fp32

    // workspace layout (fp32): att[2048] | proj_c[2048*256] | proj_e[128*256]
    float* att    = (float*)d_ws;
    float* proj_c = att + BS1 * NEC;
    float* proj_e = proj_c + BS1 * NEC * MD;

    void* args[] = { (void*)&crit, (void*)&ehr, (void*)&w_mlp, (void*)&w_align,
                     (void*)&b_mlp, (void*)&proj_c, (void*)&proj_e, (void*)&att,
                     (void*)&out };
    hipError_t err = hipLaunchCooperativeKernel((void*)fused_kernel,
                                                dim3(1024), dim3(256),
                                                args, 0, stream);
    if (err != hipSuccess) {
        (void)hipGetLastError();   // clear sticky error, use proven 2-kernel path
        prep_kernel<<<272 + BS1, 256, 0, stream>>>(crit, ehr, w_mlp, w_align,
                                                   proj_c, proj_e, att);
        final_kernel<<<BS1 * BS2, 256, 0, stream>>>(att, proj_c, proj_e, b_mlp, out);
    }
}

// Round 8
// 299.438 us; speedup vs baseline: 1.7096x; 1.7096x over previous
//
#include <hip/hip_runtime.h>

// Problem constants
#define BS1 32
#define BS2 128
#define NEC 64
#define QD  256   // Q_DIM
#define MD  256   // MLP_DIM (== MEM_DIM)

// Fused prep kernel, 256 threads/block (proven R5 structure):
//   blocks [0,256):   proj_c rows 8*blk      = crit rows @ W_mlp[:256,:]
//   blocks [256,272): proj_e rows 8*(blk-256) = ehr rows @ W_mlp[256:,:]
//   blocks [272,304): att[b,:] = softmax_e(crit[b,e,:] . W_align[:256]), b = blk-272
//                     (logit_e[p] and b_align are constant over axis e -> cancel)
__global__ __launch_bounds__(256)
void prep_kernel(const float* __restrict__ crit,
                 const float* __restrict__ ehr,
                 const float* __restrict__ w_mlp,
                 const float* __restrict__ w_align,
                 float* __restrict__ proj_c,
                 float* __restrict__ proj_e,
                 float* __restrict__ att) {
    __shared__ float smem[8 * QD];     // GEMM A-tile (8 KB) or wa[256]
    __shared__ float logits[NEC];
    int tid = threadIdx.x;
    int blk = blockIdx.x;

    if (blk < 272) {
        // ---- 8-row GEMM: out[m0:m0+8, :] = A[m0:m0+8, :] @ B ----
        const float* A; const float* B; float* out; int m0;
        if (blk < 256) { A = crit; B = w_mlp;           out = proj_c; m0 = blk * 8; }
        else           { A = ehr;  B = w_mlp + QD * MD; out = proj_e; m0 = (blk - 256) * 8; }
        {
            const float* src = A + m0 * QD + tid * 8;
            float4 a0 = *(const float4*)src;
            float4 a1 = *(const float4*)(src + 4);
            *(float4*)&smem[tid * 8]     = a0;
            *(float4*)&smem[tid * 8 + 4] = a1;
        }
        __syncthreads();
        int r = tid >> 5;            // row in [0,8)
        int c = (tid & 31) * 8;      // col base
        float acc[8] = {0.f,0.f,0.f,0.f,0.f,0.f,0.f,0.f};
        #pragma unroll 4
        for (int k = 0; k < QD; ++k) {
            float a = smem[r * QD + k];
            const float* bp = B + k * MD + c;
            float4 b0 = *(const float4*)bp;
            float4 b1 = *(const float4*)(bp + 4);
            acc[0] = fmaf(a, b0.x, acc[0]);
            acc[1] = fmaf(a, b0.y, acc[1]);
            acc[2] = fmaf(a, b0.z, acc[2]);
            acc[3] = fmaf(a, b0.w, acc[3]);
            acc[4] = fmaf(a, b1.x, acc[4]);
            acc[5] = fmaf(a, b1.y, acc[5]);
            acc[6] = fmaf(a, b1.z, acc[6]);
            acc[7] = fmaf(a, b1.w, acc[7]);
        }
        float* o = out + (m0 + r) * MD + c;
        *(float4*)o       = make_float4(acc[0], acc[1], acc[2], acc[3]);
        *(float4*)(o + 4) = make_float4(acc[4], acc[5], acc[6], acc[7]);
    } else {
        // ---- att for one b: 4 lanes per e-row ----
        int b = blk - 272;
        smem[tid] = w_align[tid];            // wa[0:256]
        __syncthreads();
        int e = tid >> 2, q = tid & 3;
        const float* row = crit + (b * NEC + e) * QD + q * 64;
        const float* w   = &smem[q * 64];
        float acc = 0.f;
        #pragma unroll
        for (int k = 0; k < 64; k += 4) {
            float4 u = *(const float4*)(row + k);
            acc = fmaf(u.x, w[k + 0], acc);
            acc = fmaf(u.y, w[k + 1], acc);
            acc = fmaf(u.z, w[k + 2], acc);
            acc = fmaf(u.w, w[k + 3], acc);
        }
        // sum the 4-lane group
        acc += __shfl_xor(acc, 1);
        acc += __shfl_xor(acc, 2);
        if (q == 0) logits[e] = acc;
        __syncthreads();
        if (tid < NEC) {                     // wave 0 does the 64-wide softmax
            float l = logits[tid];
            float m = l;
            #pragma unroll
            for (int off = 32; off; off >>= 1) m = fmaxf(m, __shfl_xor(m, off));
            float ex = __expf(l - m);
            float s = ex;
            #pragma unroll
            for (int off = 32; off; off >>= 1) s += __shfl_xor(s, off);
            att[b * NEC + tid] = ex / s;
        }
    }
}

// h[b,p,e,d] = att[b,e]*(proj_c[b,e,d] + proj_e[p,d]) + b_mlp[d]
//            = (att[b,e]*proj_c[b,e,d] + b_mlp[d]) + att[b,e]*proj_e[p,d]
// One block per (b,e): att -> 1 wave-uniform scalar; proj_c row + b_mlp folded
// into `base` registers ONCE; the p-loop only reads proj_e (128 KB, L2-hot in
// every XCD) with 4 independent loads in flight. Each wave-store = 1 KiB
// contiguous; per block 128 stores at 64 KiB stride.
__global__ __launch_bounds__(256)
void final_kernel(const float* __restrict__ att,
                  const float* __restrict__ proj_c,
                  const float* __restrict__ proj_e,
                  const float* __restrict__ b_mlp,
                  float*       __restrict__ out) {
    int tid = threadIdx.x;
    int be  = blockIdx.x;               // [0, 2048)
    int b = be >> 6, e = be & 63;
    int w = tid >> 6;                   // wave id [0,4): handles p = w, w+4, ...
    int d = (tid & 63) * 4;             // [0,256) step 4

    float a = att[b * NEC + e];         // wave-uniform (s_load)
    const float4 pc = *(const float4*)(proj_c + (b * NEC + e) * MD + d);
    const float4 bm = *(const float4*)(b_mlp + d);
    float4 base;                        // a*pc + bm, loop-invariant
    base.x = fmaf(a, pc.x, bm.x);
    base.y = fmaf(a, pc.y, bm.y);
    base.z = fmaf(a, pc.z, bm.z);
    base.w = fmaf(a, pc.w, bm.w);

    const float* pep = proj_e + w * MD + d;                       // p = w
    float* o = out + ((size_t)(b * BS2 + w) * NEC + e) * MD + d;  // out[b,p=w,e,d]
    const size_t PE_STEP = (size_t)4 * MD;          // p += 4
    const size_t O_STEP  = (size_t)4 * NEC * MD;    // p += 4

    #pragma unroll
    for (int g = 0; g < 8; ++g) {       // 8 groups x 4 p's = 32 p's per wave
        float4 q0 = *(const float4*)(pep);
        float4 q1 = *(const float4*)(pep + PE_STEP);
        float4 q2 = *(const float4*)(pep + 2 * PE_STEP);
        float4 q3 = *(const float4*)(pep + 3 * PE_STEP);
        float4 r;
        r.x = fmaf(a, q0.x, base.x); r.y = fmaf(a, q0.y, base.y);
        r.z = fmaf(a, q0.z, base.z); r.w = fmaf(a, q0.w, base.w);
        *(float4*)o = r;
        r.x = fmaf(a, q1.x, base.x); r.y = fmaf(a, q1.y, base.y);
        r.z = fmaf(a, q1.z, base.z); r.w = fmaf(a, q1.w, base.w);
        *(float4*)(o + O_STEP) = r;
        r.x = fmaf(a, q2.x, base.x); r.y = fmaf(a, q2.y, base.y);
        r.z = fmaf(a, q2.z, base.z); r.w = fmaf(a, q2.w, base.w);
        *(float4*)(o + 2 * O_STEP) = r;
        r.x = fmaf(a, q3.x, base.x); r.y = fmaf(a, q3.y, base.y);
        r.z = fmaf(a, q3.z, base.z); r.w = fmaf(a, q3.w, base.w);
        *(float4*)(o + 3 * O_STEP) = r;
        pep += 4 * PE_STEP;             // p += 16
        o   += 4 * O_STEP;
    }
}

extern "C" void kernel_launch(void* const* d_in, const int* in_sizes, int n_in,
                              void* d_out, int out_size, void* d_ws, size_t ws_size,
                              hipStream_t stream) {
    // setup_inputs order: ehr_vector, criteria, ec_mask, W_align, b_align, W_mlp, b_mlp
    const float* ehr     = (const float*)d_in[0];   // (128, 256) fp32
    const float* crit    = (const float*)d_in[1];   // (32, 64, 256) fp32
    const float* w_align = (const float*)d_in[3];   // (512,) -> use [:256]
    const float* w_mlp   = (const float*)d_in[5];   // (512, 256) row-major fp32
    const float* b_mlp   = (const float*)d_in[6];   // (256,)
    float* out = (float*)d_out;                      // (32,128,64,256) fp32

    // workspace layout (fp32): att[2048] | proj_c[2048*256] | proj_e[128*256]
    float* att    = (float*)d_ws;
    float* proj_c = att + BS1 * NEC;
    float* proj_e = proj_c + BS1 * NEC * MD;

    prep_kernel<<<272 + BS1, 256, 0, stream>>>(crit, ehr, w_mlp, w_align,
                                               proj_c, proj_e, att);
    final_kernel<<<BS1 * NEC, 256, 0, stream>>>(att, proj_c, proj_e, b_mlp, out);
}